// Round 15
// baseline (811.658 us; speedup 1.0000x reference)
//
#include <hip/hip_runtime.h>
#include <hip/hip_fp16.h>

typedef __attribute__((ext_vector_type(8))) _Float16 half8;
typedef __attribute__((ext_vector_type(4))) _Float16 half4;
typedef __attribute__((ext_vector_type(4))) float float4a;

// ---- workspace layout (elements of _Float16) ----
#define WT_PLANE 3145728
#define WS_FC    6291456
#define WS_FC_LO 6307840
#define WS_Q     6324224          // per-block Q planes: [bl][Qh 16384 | Ql 16384]
#define Q_STRIDE 32768

// ---- LDS layout (bytes), total 163840 ----
// phase A: X dbuf buf0 @0 (hi/lo 64K), buf1 @98304 (hi/lo 64K); VST @65536
// epilogue: KH @0, KL @32768, VST @65536, Q-staging linear @98304
// phase B: PT [128][256] f16 @98304 (64K);
//          PVH @98304 (16K) / PVL @114688 (16K) overlay PT rows 0-63 after barD
#define OFF_KH   0
#define OFF_KL   32768
#define OFF_VST  65536
#define OFF_XB1  98304
#define OFF_PT   98304
#define OFF_PVH  98304
#define OFF_PVL  114688
#define LDS_BYTES 163840

__device__ __forceinline__ int swz128(int r, int c) {
    return (r << 7) + ((((c >> 3) ^ r) & 7) << 4) + ((c & 7) << 1);
}
__device__ __forceinline__ int swz512(int r, int c) {
    return (r << 9) + (((((c >> 3) ^ (r & 7))) & 31) << 4) + ((c & 7) << 1);
}

// LDS-only barrier: does NOT drain vmcnt (global loads/stores stay in flight).
__device__ __forceinline__ void lds_barrier() {
    __builtin_amdgcn_sched_barrier(0);
    asm volatile("s_waitcnt lgkmcnt(0)" ::: "memory");
    __builtin_amdgcn_s_barrier();
    __builtin_amdgcn_sched_barrier(0);
}

// ---------------- prep: W -> WT (f16 hi/lo, transposed), fcw -> f16 hi/lo ----
extern "C" __global__ void __launch_bounds__(256)
va_prep(const float* __restrict__ Wq, const float* __restrict__ Wk,
        const float* __restrict__ Wv, const float* __restrict__ fcw,
        _Float16* __restrict__ ws)
{
    __shared__ float tile[16384];
    const int t = (int)threadIdx.x;
    const int blk = (int)blockIdx.x;
    if (blk < 192) {
        const int mat = blk >> 6, l = blk & 63;
        const float* W = (mat == 0 ? Wq : mat == 1 ? Wk : Wv) + l * 16384;
        #pragma unroll
        for (int i = 0; i < 16; ++i) {
            const int f = (i * 256 + t) * 4;
            *(float4a*)&tile[f] = *(const float4a*)(W + f);
        }
        __syncthreads();
        const int a = t & 63, cgp = t >> 6;
        const int obase = ((mat * 64 + l) * 64 + a) * 256;
        #pragma unroll
        for (int p = 0; p < 8; ++p) {
            const int c0 = cgp * 64 + p * 8;
            half8 hh, hl;
            #pragma unroll
            for (int q = 0; q < 8; ++q) {
                const float v = tile[(c0 + q) * 64 + a];
                const _Float16 h = (_Float16)v;
                hh[q] = h;
                hl[q] = (_Float16)(v - (float)h);
            }
            *(half8*)(ws + obase + c0) = hh;
            *(half8*)(ws + WT_PLANE + obase + c0) = hl;
        }
    } else {
        #pragma unroll
        for (int i = 0; i < 16; ++i) {
            const int f = (i * 256 + t) * 4;
            const float4a v = *(const float4a*)(fcw + f);
            half4 hh, hl;
            #pragma unroll
            for (int q = 0; q < 4; ++q) {
                const _Float16 h = (_Float16)v[q];
                hh[q] = h;
                hl[q] = (_Float16)(v[q] - (float)h);
            }
            *(half4*)(ws + WS_FC + f) = hh;
            *(half4*)(ws + WS_FC_LO + f) = hl;
        }
    }
}

// ---------------- main fused kernel ----------------
// r15: phase B restructured around 128-row chunk-pairs: each wave owns 16
// S-rows x all 256 m (sacc[16]) -> softmax fully wave-local (red exchange
// + its 2 barriers deleted); P write and PV read are SAME-WAVE rows (no
// barrier between them). Phase-B barriers 16 -> 6. S(pair1) computed in
// pair0's fc slot AFTER stores so sacc never co-lives with facc+yv.
extern "C" __global__ void
__launch_bounds__(512)
__attribute__((amdgpu_waves_per_eu(2, 2)))
va_fused(const float* __restrict__ Y,
         const float* __restrict__ bq, const float* __restrict__ bk,
         const float* __restrict__ bv,
         const float* __restrict__ gama, const float* __restrict__ fcb,
         _Float16* __restrict__ ws,
         float* __restrict__ out)
{
    extern __shared__ char smem[];
    const int tid  = (int)threadIdx.x;
    const int w    = tid >> 6;    // wave 0..7
    const int lane = tid & 63;
    const int l15  = lane & 15;
    const int kg   = lane >> 4;

    // XCD-aware swizzle (bijective): each XCD sees a stable set of 8 l's.
    const int i0 = (int)blockIdx.x;
    const int x  = i0 & 7, q0 = i0 >> 3;
    const int b  = q0 >> 3;
    const int l  = ((q0 & 7) << 3) | x;

    const size_t base = (size_t)b * (256u * 16384u) + (size_t)l * 256u;
    const float* __restrict__ Yb = Y + base;
    float* __restrict__ Ob = out + base;
    const size_t qslot = (size_t)WS_Q + (size_t)((b << 6) | l) * Q_STRIDE;

    const int rg = w >> 2;   // phase A: row-group (rows rg*128..+127)
    const int cg = w & 3;    // phase A: a-subgroup

    // ============ Phase A: QKV = X * W (dbuf X, split-f16 MFMA) ============
    float4a acc[8][3];
    #pragma unroll
    for (int rt = 0; rt < 8; ++rt)
        #pragma unroll
        for (int ct = 0; ct < 3; ++ct) acc[rt][ct] = (float4a)0.0f;

    const int srow = tid >> 1;          // 0..255
    const int scol = (tid & 1) * 32;
    const float* xsrc = Yb + (size_t)srow * 16384 + scol;

    auto xstage = [&](const float4a* xr, int bufbase) {
        #pragma unroll
        for (int p = 0; p < 8; ++p) {
            const int c = scol + p * 4;
            half4 hh, hl;
            #pragma unroll
            for (int q = 0; q < 4; ++q) {
                const float v = xr[p][q];
                const _Float16 h = (_Float16)v;
                hh[q] = h;
                hl[q] = (_Float16)(v - (float)h);
            }
            *(half4*)(smem + bufbase + swz128(srow, c)) = hh;
            *(half4*)(smem + bufbase + 32768 + swz128(srow, c)) = hl;
        }
    };
    auto wload = [&](int kt, int ks, half8* bh, half8* bl) {
        #pragma unroll
        for (int ct = 0; ct < 3; ++ct) {
            const int widx = ((ct * 64 + l) * 64 + cg * 16 + l15) * 256
                             + kt * 64 + ks * 32 + kg * 8;
            bh[ct] = *(const half8*)(ws + widx);
            if (ct < 2) bl[ct] = *(const half8*)(ws + WT_PLANE + widx);
        }
    };
    auto acompute = [&](int bufbase, int coff, const half8* bh, const half8* bl) {
        #pragma unroll
        for (int rt = 0; rt < 8; ++rt) {
            const int row = rg * 128 + rt * 16 + l15;
            const half8 ah = *(const half8*)(smem + bufbase + swz128(row, coff + kg * 8));
            const half8 al = *(const half8*)(smem + bufbase + 32768 + swz128(row, coff + kg * 8));
            #pragma unroll
            for (int ct = 0; ct < 2; ++ct) {
                acc[rt][ct] = __builtin_amdgcn_mfma_f32_16x16x32_f16(ah, bh[ct], acc[rt][ct], 0, 0, 0);
                acc[rt][ct] = __builtin_amdgcn_mfma_f32_16x16x32_f16(ah, bl[ct], acc[rt][ct], 0, 0, 0);
                acc[rt][ct] = __builtin_amdgcn_mfma_f32_16x16x32_f16(al, bh[ct], acc[rt][ct], 0, 0, 0);
            }
            acc[rt][2] = __builtin_amdgcn_mfma_f32_16x16x32_f16(ah, bh[2], acc[rt][2], 0, 0, 0);
            acc[rt][2] = __builtin_amdgcn_mfma_f32_16x16x32_f16(al, bh[2], acc[rt][2], 0, 0, 0);
        }
    };

    {
        float4a xr[8];
        #pragma unroll
        for (int p = 0; p < 8; ++p) xr[p] = *(const float4a*)(xsrc + p * 4);
        xstage(xr, 0);
        lds_barrier();
        #pragma unroll
        for (int p = 0; p < 8; ++p) xr[p] = *(const float4a*)(xsrc + 64 + p * 4);

        #pragma unroll 2
        for (int kt = 0; kt < 4; ++kt) {
            const int cur = (kt & 1) ? OFF_XB1 : 0;
            const int nxt = (kt & 1) ? 0 : OFF_XB1;
            if (kt < 3) xstage(xr, nxt);
            half8 bh0[3], bl0[2];
            wload(kt, 0, bh0, bl0);
            acompute(cur, 0, bh0, bl0);
            if (kt < 2) {
                #pragma unroll
                for (int p = 0; p < 8; ++p)
                    xr[p] = *(const float4a*)(xsrc + (kt + 2) * 64 + p * 4);
            }
            half8 bh1[3], bl1[2];
            wload(kt, 1, bh1, bl1);
            acompute(cur, 32, bh1, bl1);
            lds_barrier();
        }
    }

    // ---- epilogue: bias; K hi/lo + V^T -> LDS; Q -> linear staging @buf1 ----
    {
        const int a = cg * 16 + l15;
        const float biq = bq[a], bik = bk[a], biv = bv[a];
        #pragma unroll
        for (int rt = 0; rt < 8; ++rt) {
            #pragma unroll
            for (int jj = 0; jj < 4; ++jj) {
                const int m = rg * 128 + rt * 16 + kg * 4 + jj;
                const float qv = acc[rt][0][jj] + biq;
                const _Float16 qh_ = (_Float16)qv;
                *(_Float16*)(smem + OFF_XB1 + m * 128 + a * 2) = qh_;
                *(_Float16*)(smem + OFF_XB1 + 32768 + m * 128 + a * 2) =
                    (_Float16)(qv - (float)qh_);
                const float kv = acc[rt][1][jj] + bik;
                const _Float16 kh = (_Float16)kv;
                *(_Float16*)(smem + OFF_KH + swz128(m, a)) = kh;
                *(_Float16*)(smem + OFF_KL + swz128(m, a)) = (_Float16)(kv - (float)kh);
            }
            const int m0 = rg * 128 + rt * 16 + kg * 4;
            half4 vh;
            #pragma unroll
            for (int jj = 0; jj < 4; ++jj)
                vh[jj] = (_Float16)(acc[rt][2][jj] + biv);
            *(half4*)(smem + OFF_VST + swz512(a, m0)) = vh;
        }
    }
    lds_barrier();
    // coalesced Q export: LDS -> ws plane (half8 stores)
    {
        _Float16* pQhw = ws + qslot;
        _Float16* pQlw = pQhw + 16384;
        #pragma unroll
        for (int p = 0; p < 4; ++p) {
            const int e = tid * 32 + p * 8;
            *(half8*)(pQhw + e) = *(const half8*)(smem + OFF_XB1 + e * 2);
            *(half8*)(pQlw + e) = *(const half8*)(smem + OFF_XB1 + 32768 + e * 2);
        }
    }
    __syncthreads();   // full drain: Q stores visible (L2) to all waves' loads

    // ---- phase B constants ----
    const int rtf = w & 3;     // fc: row-tile within 64-row subchunk
    const int cgf = w >> 2;    // fc: col-half (cc cgf*128..+127)
    const float gv = gama[0];
    float fcbv[8];
    #pragma unroll
    for (int i = 0; i < 8; ++i) fcbv[i] = fcb[cgf * 128 + i * 16 + l15];
    const _Float16* __restrict__ pQh = ws + qslot;
    const _Float16* __restrict__ pQl = pQh + 16384;

    half8 qfh[2], qfl[2];      // Q fragments: wave's 16 rows of current pair
    auto loadQ = [&](int cp) {
        const int arow = cp * 128 + w * 16 + l15;
        #pragma unroll
        for (int ks = 0; ks < 2; ++ks) {
            const int a0 = ks * 32 + kg * 8;
            qfh[ks] = *(const half8*)(pQh + arow * 64 + a0);
            qfl[ks] = *(const half8*)(pQl + arow * 64 + a0);
        }
    };
    // full-row S for the wave's 16 rows (3-term split-f16 MFMA)
    auto computeS = [&](float4a* sacc) {
        #pragma unroll
        for (int mt = 0; mt < 16; ++mt) sacc[mt] = (float4a)0.0f;
        #pragma unroll
        for (int ks = 0; ks < 2; ++ks) {
            const int a0 = ks * 32 + kg * 8;
            const half8 ah = qfh[ks];
            const half8 al = qfl[ks];
            #pragma unroll
            for (int mt = 0; mt < 16; ++mt) {
                const int mcol = mt * 16 + l15;
                const half8 bh = *(const half8*)(smem + OFF_KH + swz128(mcol, a0));
                const half8 bl = *(const half8*)(smem + OFF_KL + swz128(mcol, a0));
                sacc[mt] = __builtin_amdgcn_mfma_f32_16x16x32_f16(ah, bh, sacc[mt], 0, 0, 0);
                sacc[mt] = __builtin_amdgcn_mfma_f32_16x16x32_f16(ah, bl, sacc[mt], 0, 0, 0);
                sacc[mt] = __builtin_amdgcn_mfma_f32_16x16x32_f16(al, bh, sacc[mt], 0, 0, 0);
            }
        }
    };

    // ---- prologue: Q(0) fragments + S(0) ----
    loadQ(0);
    float4a sacc[16];
    computeS(sacc);

    // ============ Phase B: 2 chunk-pairs of 128 rows ============
    #pragma unroll 1
    for (int cp = 0; cp < 2; ++cp) {
        // ---- 1. wave-local softmax (no LDS, no barrier) ----
        float fac[4];
        #pragma unroll
        for (int jj = 0; jj < 4; ++jj) {
            float m0 = sacc[0][jj];
            #pragma unroll
            for (int mt = 1; mt < 16; ++mt) m0 = fmaxf(m0, sacc[mt][jj]);
            m0 = fmaxf(m0, __shfl_xor(m0, 1));
            m0 = fmaxf(m0, __shfl_xor(m0, 2));
            m0 = fmaxf(m0, __shfl_xor(m0, 4));
            m0 = fmaxf(m0, __shfl_xor(m0, 8));
            fac[jj] = m0;   // temporarily holds row max
        }
        #pragma unroll
        for (int mt = 0; mt < 16; ++mt)
            #pragma unroll
            for (int jj = 0; jj < 4; ++jj)
                sacc[mt][jj] = __expf(sacc[mt][jj] - fac[jj]);
        #pragma unroll
        for (int jj = 0; jj < 4; ++jj) {
            float s0 = 0.0f;
            #pragma unroll
            for (int mt = 0; mt < 16; ++mt) s0 += sacc[mt][jj];
            s0 += __shfl_xor(s0, 1);
            s0 += __shfl_xor(s0, 2);
            s0 += __shfl_xor(s0, 4);
            s0 += __shfl_xor(s0, 8);
            fac[jj] = 1.0f / s0;
        }
        // ---- 2. normalized P -> PT [128][256] (wave-own rows) ----
        #pragma unroll
        for (int jj = 0; jj < 4; ++jj) {
            const int rloc = w * 16 + kg * 4 + jj;
            #pragma unroll
            for (int mt = 0; mt < 16; ++mt) {
                const int mcol = mt * 16 + l15;
                *(_Float16*)(smem + OFF_PT + swz512(rloc, mcol)) =
                    (_Float16)(sacc[mt][jj] * fac[jj]);
            }
        }
        if (cp == 0) loadQ(1);   // global loads, in flight across barriers

        // ---- 3. PV: reads PT rows w*16..+15 (same wave wrote them) + VST ----
        float4a pacc[4];
        #pragma unroll
        for (int at = 0; at < 4; ++at) pacc[at] = (float4a)0.0f;
        #pragma unroll
        for (int ks = 0; ks < 8; ++ks) {
            const int mk = ks * 32 + kg * 8;
            const half8 pa = *(const half8*)(smem + OFF_PT + swz512(w * 16 + l15, mk));
            #pragma unroll
            for (int at = 0; at < 4; ++at) {
                const half8 vb = *(const half8*)(smem + OFF_VST + swz512(at * 16 + l15, mk));
                pacc[at] = __builtin_amdgcn_mfma_f32_16x16x32_f16(pa, vb, pacc[at], 0, 0, 0);
            }
        }
        lds_barrier();                                       // barD: all PT reads done
        #pragma unroll
        for (int at = 0; at < 4; ++at)
            #pragma unroll
            for (int jj = 0; jj < 4; ++jj) {
                const int rloc = w * 16 + kg * 4 + jj;
                const int colp = at * 16 + l15;
                const float pv = pacc[at][jj];
                const _Float16 ph = (_Float16)pv;
                *(_Float16*)(smem + OFF_PVH + swz128(rloc, colp)) = ph;
                *(_Float16*)(smem + OFF_PVL + swz128(rloc, colp)) = (_Float16)(pv - (float)ph);
            }
        lds_barrier();                                       // barE: PVH/PVL ready

        // ---- 4. fc (3-term MFMA) + direct gated-residual store, 2 subchunks ----
        #pragma unroll 1
        for (int sc = 0; sc < 2; ++sc) {
            const int rbase = cp * 128 + sc * 64 + rtf * 16;
            float yv[8][4];
            #pragma unroll
            for (int i = 0; i < 8; ++i)
                #pragma unroll
                for (int jj = 0; jj < 4; ++jj)
                    yv[i][jj] = Yb[(size_t)(rbase + kg * 4 + jj) * 16384
                                   + cgf * 128 + i * 16 + l15];
            float4a facc[8];
            #pragma unroll
            for (int i = 0; i < 8; ++i) facc[i] = (float4a)0.0f;
            #pragma unroll
            for (int ks = 0; ks < 2; ++ks) {
                const int aoff = ks * 32 + kg * 8;
                const half8 ah = *(const half8*)(smem + OFF_PVH + swz128(sc * 64 + rtf * 16 + l15, aoff));
                const half8 al = *(const half8*)(smem + OFF_PVL + swz128(sc * 64 + rtf * 16 + l15, aoff));
                #pragma unroll
                for (int i = 0; i < 8; ++i) {
                    const int cc = cgf * 128 + i * 16 + l15;
                    const half8 bfh = *(const half8*)(ws + WS_FC + cc * 64 + aoff);
                    const half8 bfl = *(const half8*)(ws + WS_FC_LO + cc * 64 + aoff);
                    facc[i] = __builtin_amdgcn_mfma_f32_16x16x32_f16(ah, bfh, facc[i], 0, 0, 0);
                    facc[i] = __builtin_amdgcn_mfma_f32_16x16x32_f16(al, bfh, facc[i], 0, 0, 0);
                    facc[i] = __builtin_amdgcn_mfma_f32_16x16x32_f16(ah, bfl, facc[i], 0, 0, 0);
                }
            }
            #pragma unroll
            for (int i = 0; i < 8; ++i)
                #pragma unroll
                for (int jj = 0; jj < 4; ++jj) {
                    const int row = rbase + kg * 4 + jj;
                    const int col = cgf * 128 + i * 16 + l15;
                    Ob[(size_t)row * 16384 + col] =
                        yv[i][jj] + gv * (facc[i][jj] + fcbv[i]);
                }
        }
        // S for next pair: after fc (facc/yv dead) so sacc[16] doesn't
        // co-live with them (r12 spill lesson). Reads stable KH/KL + Q regs.
        __builtin_amdgcn_sched_barrier(0);
        if (cp == 0) computeS(sacc);
        lds_barrier();                                       // barF: fc's PVH reads
                                                             // done before next PT write
    }
}

extern "C" void kernel_launch(void* const* d_in, const int* in_sizes, int n_in,
                              void* d_out, int out_size, void* d_ws, size_t ws_size,
                              hipStream_t stream) {
    (void)in_sizes; (void)n_in; (void)ws_size; (void)out_size;
    const float* Y    = (const float*)d_in[0];
    const float* Wq   = (const float*)d_in[1];
    const float* Wk   = (const float*)d_in[2];
    const float* Wv   = (const float*)d_in[3];
    const float* bq   = (const float*)d_in[4];
    const float* bk   = (const float*)d_in[5];
    const float* bv   = (const float*)d_in[6];
    const float* gama = (const float*)d_in[7];
    const float* fcw  = (const float*)d_in[8];
    const float* fcb  = (const float*)d_in[9];
    float* outp = (float*)d_out;
    _Float16* ws = (_Float16*)d_ws;

    (void)hipFuncSetAttribute((const void*)va_fused,
                              hipFuncAttributeMaxDynamicSharedMemorySize, LDS_BYTES);

    va_prep<<<dim3(193), dim3(256), 0, stream>>>(Wq, Wk, Wv, fcw, ws);
    va_fused<<<dim3(1024), dim3(512), LDS_BYTES, stream>>>(
        Y, bq, bk, bv, gama, fcb, ws, outp);
}

// Round 16
// 312.753 us; speedup vs baseline: 2.5952x; 2.5952x over previous
//
#include <hip/hip_runtime.h>
#include <hip/hip_fp16.h>

typedef __attribute__((ext_vector_type(8))) _Float16 half8;
typedef __attribute__((ext_vector_type(4))) _Float16 half4;
typedef __attribute__((ext_vector_type(4))) float float4a;

// ---- workspace layout (elements of _Float16) ----
#define WT_PLANE 3145728
#define WS_FC    6291456
#define WS_FC_LO 6307840
#define WS_Q     6324224          // per-block Q planes: [bl][Qh 16384 | Ql 16384]
#define Q_STRIDE 32768

// ---- LDS layout (bytes), total 163840 ----
#define OFF_KH   0
#define OFF_KL   32768
#define OFF_VST  65536
#define OFF_XB1  98304
#define OFF_PT   114688
#define OFF_PVH  147456
#define OFF_RED1 147456   // aliases PVH; fenced by barE/barB ordering (r14-verified)
#define OFF_RED2 148480
#define LDS_BYTES 163840

__device__ __forceinline__ int swz128(int r, int c) {
    return (r << 7) + ((((c >> 3) ^ r) & 7) << 4) + ((c & 7) << 1);
}
__device__ __forceinline__ int swz512(int r, int c) {
    return (r << 9) + (((((c >> 3) ^ (r & 7))) & 31) << 4) + ((c & 7) << 1);
}

// LDS-only barrier: does NOT drain vmcnt (global loads/stores stay in flight).
__device__ __forceinline__ void lds_barrier() {
    __builtin_amdgcn_sched_barrier(0);
    asm volatile("s_waitcnt lgkmcnt(0)" ::: "memory");
    __builtin_amdgcn_s_barrier();
    __builtin_amdgcn_sched_barrier(0);
}

// ---------------- prep: W -> WT (f16 hi/lo, transposed), fcw -> f16 hi/lo ----
extern "C" __global__ void __launch_bounds__(256)
va_prep(const float* __restrict__ Wq, const float* __restrict__ Wk,
        const float* __restrict__ Wv, const float* __restrict__ fcw,
        _Float16* __restrict__ ws)
{
    __shared__ float tile[16384];
    const int t = (int)threadIdx.x;
    const int blk = (int)blockIdx.x;
    if (blk < 192) {
        const int mat = blk >> 6, l = blk & 63;
        const float* W = (mat == 0 ? Wq : mat == 1 ? Wk : Wv) + l * 16384;
        #pragma unroll
        for (int i = 0; i < 16; ++i) {
            const int f = (i * 256 + t) * 4;
            *(float4a*)&tile[f] = *(const float4a*)(W + f);
        }
        __syncthreads();
        const int a = t & 63, cgp = t >> 6;
        const int obase = ((mat * 64 + l) * 64 + a) * 256;
        #pragma unroll
        for (int p = 0; p < 8; ++p) {
            const int c0 = cgp * 64 + p * 8;
            half8 hh, hl;
            #pragma unroll
            for (int q = 0; q < 8; ++q) {
                const float v = tile[(c0 + q) * 64 + a];
                const _Float16 h = (_Float16)v;
                hh[q] = h;
                hl[q] = (_Float16)(v - (float)h);
            }
            *(half8*)(ws + obase + c0) = hh;
            *(half8*)(ws + WT_PLANE + obase + c0) = hl;
        }
    } else {
        #pragma unroll
        for (int i = 0; i < 16; ++i) {
            const int f = (i * 256 + t) * 4;
            const float4a v = *(const float4a*)(fcw + f);
            half4 hh, hl;
            #pragma unroll
            for (int q = 0; q < 4; ++q) {
                const _Float16 h = (_Float16)v[q];
                hh[q] = h;
                hl[q] = (_Float16)(v[q] - (float)h);
            }
            *(half4*)(ws + WS_FC + f) = hh;
            *(half4*)(ws + WS_FC_LO + f) = hl;
        }
    }
}

// ---------------- main fused kernel ----------------
// r16: r14 exactly (best known, 445us) + single-precision fc path:
//  - PV stored single f16 (PVL deleted): dropped PV-lo term contributes
//    ~sqrt(64)*|PV|*|w|*2^-12 ~= 0.01-0.05 abs, far under the 1.035
//    threshold (current absmax 0.25).
//  - fc single-term (PVh*Wh): 48->16 MFMAs/chunk/wave; W-lo loads gone
//    from the critical post-barD fc phase.
// r15 lesson locked in: phase-B accumulators >32 f32 regs spill; revert.
extern "C" __global__ void
__launch_bounds__(512)
__attribute__((amdgpu_waves_per_eu(2, 2)))
va_fused(const float* __restrict__ Y,
         const float* __restrict__ bq, const float* __restrict__ bk,
         const float* __restrict__ bv,
         const float* __restrict__ gama, const float* __restrict__ fcb,
         _Float16* __restrict__ ws,
         float* __restrict__ out)
{
    extern __shared__ char smem[];
    const int tid  = (int)threadIdx.x;
    const int w    = tid >> 6;    // wave 0..7
    const int lane = tid & 63;
    const int l15  = lane & 15;
    const int kg   = lane >> 4;

    // XCD-aware swizzle (bijective): each XCD sees a stable set of 8 l's.
    const int i0 = (int)blockIdx.x;
    const int x  = i0 & 7, q0 = i0 >> 3;
    const int b  = q0 >> 3;
    const int l  = ((q0 & 7) << 3) | x;

    const size_t base = (size_t)b * (256u * 16384u) + (size_t)l * 256u;
    const float* __restrict__ Yb = Y + base;
    float* __restrict__ Ob = out + base;
    const size_t qslot = (size_t)WS_Q + (size_t)((b << 6) | l) * Q_STRIDE;

    const int rg = w >> 2;   // phase A: row-group (rows rg*128..+127)
    const int cg = w & 3;    // phase A: a-subgroup

    // ============ Phase A: QKV = X * W (dbuf X, split-f16 MFMA) ============
    float4a acc[8][3];
    #pragma unroll
    for (int rt = 0; rt < 8; ++rt)
        #pragma unroll
        for (int ct = 0; ct < 3; ++ct) acc[rt][ct] = (float4a)0.0f;

    const int srow = tid >> 1;          // 0..255
    const int scol = (tid & 1) * 32;
    const float* xsrc = Yb + (size_t)srow * 16384 + scol;

    auto xstage = [&](const float4a* xr, int bufbase) {
        #pragma unroll
        for (int p = 0; p < 8; ++p) {
            const int c = scol + p * 4;
            half4 hh, hl;
            #pragma unroll
            for (int q = 0; q < 4; ++q) {
                const float v = xr[p][q];
                const _Float16 h = (_Float16)v;
                hh[q] = h;
                hl[q] = (_Float16)(v - (float)h);
            }
            *(half4*)(smem + bufbase + swz128(srow, c)) = hh;
            *(half4*)(smem + bufbase + 32768 + swz128(srow, c)) = hl;
        }
    };
    auto wload = [&](int kt, int ks, half8* bh, half8* bl) {
        #pragma unroll
        for (int ct = 0; ct < 3; ++ct) {
            const int widx = ((ct * 64 + l) * 64 + cg * 16 + l15) * 256
                             + kt * 64 + ks * 32 + kg * 8;
            bh[ct] = *(const half8*)(ws + widx);
            if (ct < 2) bl[ct] = *(const half8*)(ws + WT_PLANE + widx);
        }
    };
    auto acompute = [&](int bufbase, int coff, const half8* bh, const half8* bl) {
        #pragma unroll
        for (int rt = 0; rt < 8; ++rt) {
            const int row = rg * 128 + rt * 16 + l15;
            const half8 ah = *(const half8*)(smem + bufbase + swz128(row, coff + kg * 8));
            const half8 al = *(const half8*)(smem + bufbase + 32768 + swz128(row, coff + kg * 8));
            #pragma unroll
            for (int ct = 0; ct < 2; ++ct) {
                acc[rt][ct] = __builtin_amdgcn_mfma_f32_16x16x32_f16(ah, bh[ct], acc[rt][ct], 0, 0, 0);
                acc[rt][ct] = __builtin_amdgcn_mfma_f32_16x16x32_f16(ah, bl[ct], acc[rt][ct], 0, 0, 0);
                acc[rt][ct] = __builtin_amdgcn_mfma_f32_16x16x32_f16(al, bh[ct], acc[rt][ct], 0, 0, 0);
            }
            acc[rt][2] = __builtin_amdgcn_mfma_f32_16x16x32_f16(ah, bh[2], acc[rt][2], 0, 0, 0);
            acc[rt][2] = __builtin_amdgcn_mfma_f32_16x16x32_f16(al, bh[2], acc[rt][2], 0, 0, 0);
        }
    };

    {
        float4a xr[8];
        #pragma unroll
        for (int p = 0; p < 8; ++p) xr[p] = *(const float4a*)(xsrc + p * 4);
        xstage(xr, 0);
        lds_barrier();
        #pragma unroll
        for (int p = 0; p < 8; ++p) xr[p] = *(const float4a*)(xsrc + 64 + p * 4);

        #pragma unroll 2
        for (int kt = 0; kt < 4; ++kt) {
            const int cur = (kt & 1) ? OFF_XB1 : 0;
            const int nxt = (kt & 1) ? 0 : OFF_XB1;
            if (kt < 3) xstage(xr, nxt);
            half8 bh0[3], bl0[2];
            wload(kt, 0, bh0, bl0);
            acompute(cur, 0, bh0, bl0);
            if (kt < 2) {
                #pragma unroll
                for (int p = 0; p < 8; ++p)
                    xr[p] = *(const float4a*)(xsrc + (kt + 2) * 64 + p * 4);
            }
            half8 bh1[3], bl1[2];
            wload(kt, 1, bh1, bl1);
            acompute(cur, 32, bh1, bl1);
            lds_barrier();
        }
    }

    // ---- epilogue: bias; K hi/lo + V^T -> LDS; Q -> linear staging @buf1 ----
    {
        const int a = cg * 16 + l15;
        const float biq = bq[a], bik = bk[a], biv = bv[a];
        #pragma unroll
        for (int rt = 0; rt < 8; ++rt) {
            #pragma unroll
            for (int jj = 0; jj < 4; ++jj) {
                const int m = rg * 128 + rt * 16 + kg * 4 + jj;
                const float qv = acc[rt][0][jj] + biq;
                const _Float16 qh_ = (_Float16)qv;
                *(_Float16*)(smem + OFF_XB1 + m * 128 + a * 2) = qh_;
                *(_Float16*)(smem + OFF_XB1 + 32768 + m * 128 + a * 2) =
                    (_Float16)(qv - (float)qh_);
                const float kv = acc[rt][1][jj] + bik;
                const _Float16 kh = (_Float16)kv;
                *(_Float16*)(smem + OFF_KH + swz128(m, a)) = kh;
                *(_Float16*)(smem + OFF_KL + swz128(m, a)) = (_Float16)(kv - (float)kh);
            }
            const int m0 = rg * 128 + rt * 16 + kg * 4;
            half4 vh;
            #pragma unroll
            for (int jj = 0; jj < 4; ++jj)
                vh[jj] = (_Float16)(acc[rt][2][jj] + biv);
            *(half4*)(smem + OFF_VST + swz512(a, m0)) = vh;
        }
    }
    lds_barrier();
    // coalesced Q export: LDS -> ws plane (half8 stores)
    {
        _Float16* pQhw = ws + qslot;
        _Float16* pQlw = pQhw + 16384;
        #pragma unroll
        for (int p = 0; p < 4; ++p) {
            const int e = tid * 32 + p * 8;
            *(half8*)(pQhw + e) = *(const half8*)(smem + OFF_XB1 + e * 2);
            *(half8*)(pQlw + e) = *(const half8*)(smem + OFF_XB1 + 32768 + e * 2);
        }
    }
    __syncthreads();   // full drain: Q stores visible (L2) to all waves' loads

    // ---- phase B constants ----
    const int rt_s = w & 3;    // chunk-local row-tile
    const int mq   = w >> 2;   // S: m-half
    const int ah2  = w >> 2;   // PV: a-half
    const int cgf  = w >> 2;   // fc: col-half (cc cgf*128..+127)
    const float gv = gama[0];
    float fcbv[8];
    #pragma unroll
    for (int i = 0; i < 8; ++i) fcbv[i] = fcb[cgf * 128 + i * 16 + l15];
    float* red1 = (float*)(smem + OFF_RED1);
    float* red2 = (float*)(smem + OFF_RED2);
    const _Float16* __restrict__ pQh = ws + qslot;
    const _Float16* __restrict__ pQl = pQh + 16384;

    half8 qfh[2], qfl[2];      // prefetched Q fragments for the chunk in flight
    auto loadQ = [&](int ci) {
        const int arow = ci * 64 + rt_s * 16 + l15;
        #pragma unroll
        for (int ks = 0; ks < 2; ++ks) {
            const int a0 = ks * 32 + kg * 8;
            qfh[ks] = *(const half8*)(pQh + arow * 64 + a0);
            qfl[ks] = *(const half8*)(pQl + arow * 64 + a0);
        }
    };
    // S = Q K^T (3-term split-f16 MFMA); Q from regs, K from stable LDS
    auto computeS = [&](float4a* sacc) {
        #pragma unroll
        for (int mt = 0; mt < 8; ++mt) sacc[mt] = (float4a)0.0f;
        #pragma unroll
        for (int ks = 0; ks < 2; ++ks) {
            const int a0 = ks * 32 + kg * 8;
            const half8 ah = qfh[ks];
            const half8 al = qfl[ks];
            #pragma unroll
            for (int mt = 0; mt < 8; ++mt) {
                const int mcol = mq * 128 + mt * 16 + l15;
                const half8 bh = *(const half8*)(smem + OFF_KH + swz128(mcol, a0));
                const half8 bl = *(const half8*)(smem + OFF_KL + swz128(mcol, a0));
                sacc[mt] = __builtin_amdgcn_mfma_f32_16x16x32_f16(ah, bh, sacc[mt], 0, 0, 0);
                sacc[mt] = __builtin_amdgcn_mfma_f32_16x16x32_f16(ah, bl, sacc[mt], 0, 0, 0);
                sacc[mt] = __builtin_amdgcn_mfma_f32_16x16x32_f16(al, bh, sacc[mt], 0, 0, 0);
            }
        }
    };

    // ---- prologue: Q(0) fragments + S(0) ----
    loadQ(0);
    float4a sacc[8];
    computeS(sacc);

    // ============ Phase B: 4 chunks; S(ci+1) overlapped with fc(ci) ============
    #pragma unroll 1
    for (int ci = 0; ci < 4; ++ci) {
        // ---- 1. softmax partials on sacc + red write ----
        float mloc[4];
        #pragma unroll
        for (int jj = 0; jj < 4; ++jj) {
            float m0 = sacc[0][jj];
            #pragma unroll
            for (int mt = 1; mt < 8; ++mt) m0 = fmaxf(m0, sacc[mt][jj]);
            m0 = fmaxf(m0, __shfl_xor(m0, 1));
            m0 = fmaxf(m0, __shfl_xor(m0, 2));
            m0 = fmaxf(m0, __shfl_xor(m0, 4));
            m0 = fmaxf(m0, __shfl_xor(m0, 8));
            mloc[jj] = m0;
        }
        #pragma unroll
        for (int mt = 0; mt < 8; ++mt)
            #pragma unroll
            for (int jj = 0; jj < 4; ++jj)
                sacc[mt][jj] = __expf(sacc[mt][jj] - mloc[jj]);
        #pragma unroll
        for (int jj = 0; jj < 4; ++jj) {
            float s0 = 0.0f;
            #pragma unroll
            for (int mt = 0; mt < 8; ++mt) s0 += sacc[mt][jj];
            s0 += __shfl_xor(s0, 1);
            s0 += __shfl_xor(s0, 2);
            s0 += __shfl_xor(s0, 4);
            s0 += __shfl_xor(s0, 8);
            if (l15 == 0) {
                const int rloc = rt_s * 16 + kg * 4 + jj;
                red1[rloc * 2 + mq] = mloc[jj];
                red2[rloc * 2 + mq] = s0;
            }
        }
        lds_barrier();                                       // barB

        // ---- 2. normalize + PT write; Q(ci+1) prefetch; yv loads ----
        #pragma unroll
        for (int jj = 0; jj < 4; ++jj) {
            const int rloc = rt_s * 16 + kg * 4 + jj;
            const float rm0 = red1[rloc * 2], rm1 = red1[rloc * 2 + 1];
            const float rs0 = red2[rloc * 2], rs1 = red2[rloc * 2 + 1];
            const float gmax = fmaxf(rm0, rm1);
            const float total = rs0 * __expf(rm0 - gmax) + rs1 * __expf(rm1 - gmax);
            const float fac = __expf(mloc[jj] - gmax) / total;
            #pragma unroll
            for (int mt = 0; mt < 8; ++mt) {
                const int mcol = mq * 128 + mt * 16 + l15;
                *(_Float16*)(smem + OFF_PT + swz512(rloc, mcol)) =
                    (_Float16)(sacc[mt][jj] * fac);
            }
        }
        if (ci < 3) loadQ(ci + 1);   // in flight across barC/barD (no vmcnt drain)
        float yv[8][4];
        #pragma unroll
        for (int i = 0; i < 8; ++i)
            #pragma unroll
            for (int jj = 0; jj < 4; ++jj) {
                const int row = ci * 64 + rt_s * 16 + kg * 4 + jj;
                const int col = cgf * 128 + i * 16 + l15;
                yv[i][jj] = Yb[(size_t)row * 16384 + col];
            }
        lds_barrier();                                       // barC

        // ---- 3. PV = P * V -> PVH (single f16: PV-lo term dropped; error
        //         ~0.01-0.05 abs, well under threshold) ----
        float4a pacc[2];
        pacc[0] = (float4a)0.0f; pacc[1] = (float4a)0.0f;
        #pragma unroll
        for (int ks = 0; ks < 8; ++ks) {
            const int mk = ks * 32 + kg * 8;
            const half8 pa = *(const half8*)(smem + OFF_PT + swz512(rt_s * 16 + l15, mk));
            #pragma unroll
            for (int i = 0; i < 2; ++i) {
                const half8 vb = *(const half8*)(smem + OFF_VST + swz512((ah2 * 2 + i) * 16 + l15, mk));
                pacc[i] = __builtin_amdgcn_mfma_f32_16x16x32_f16(pa, vb, pacc[i], 0, 0, 0);
            }
        }
        #pragma unroll
        for (int i = 0; i < 2; ++i)
            #pragma unroll
            for (int jj = 0; jj < 4; ++jj) {
                const int rloc = rt_s * 16 + kg * 4 + jj;
                const int colp = (ah2 * 2 + i) * 16 + l15;
                *(_Float16*)(smem + OFF_PVH + swz128(rloc, colp)) =
                    (_Float16)pacc[i][jj];
            }
        lds_barrier();                                       // barD

        // ---- 4. fc(ci) single-term MFMA + S(ci+1) MFMA + store ----
        if (ci < 3) computeS(sacc);   // reads stable KH/KL + prefetched Q regs
        float4a facc[8];
        #pragma unroll
        for (int i = 0; i < 8; ++i) facc[i] = (float4a)0.0f;
        #pragma unroll
        for (int ks = 0; ks < 2; ++ks) {
            const int aoff = ks * 32 + kg * 8;
            const half8 ah = *(const half8*)(smem + OFF_PVH + swz128(rt_s * 16 + l15, aoff));
            #pragma unroll
            for (int i = 0; i < 8; ++i) {
                const int cc = cgf * 128 + i * 16 + l15;
                const half8 bfh = *(const half8*)(ws + WS_FC + cc * 64 + aoff);
                facc[i] = __builtin_amdgcn_mfma_f32_16x16x32_f16(ah, bfh, facc[i], 0, 0, 0);
            }
        }
        #pragma unroll
        for (int i = 0; i < 8; ++i)
            #pragma unroll
            for (int jj = 0; jj < 4; ++jj) {
                const int row = ci * 64 + rt_s * 16 + kg * 4 + jj;
                const int col = cgf * 128 + i * 16 + l15;
                Ob[(size_t)row * 16384 + col] =
                    yv[i][jj] + gv * (facc[i][jj] + fcbv[i]);
            }
        lds_barrier();                                       // barE
        // barE: next chunk's red write (aliases PVH) vs this fc's PVH reads.
    }
}

extern "C" void kernel_launch(void* const* d_in, const int* in_sizes, int n_in,
                              void* d_out, int out_size, void* d_ws, size_t ws_size,
                              hipStream_t stream) {
    (void)in_sizes; (void)n_in; (void)ws_size; (void)out_size;
    const float* Y    = (const float*)d_in[0];
    const float* Wq   = (const float*)d_in[1];
    const float* Wk   = (const float*)d_in[2];
    const float* Wv   = (const float*)d_in[3];
    const float* bq   = (const float*)d_in[4];
    const float* bk   = (const float*)d_in[5];
    const float* bv   = (const float*)d_in[6];
    const float* gama = (const float*)d_in[7];
    const float* fcw  = (const float*)d_in[8];
    const float* fcb  = (const float*)d_in[9];
    float* outp = (float*)d_out;
    _Float16* ws = (_Float16*)d_ws;

    (void)hipFuncSetAttribute((const void*)va_fused,
                              hipFuncAttributeMaxDynamicSharedMemorySize, LDS_BYTES);

    va_prep<<<dim3(193), dim3(256), 0, stream>>>(Wq, Wk, Wv, fcw, ws);
    va_fused<<<dim3(1024), dim3(512), LDS_BYTES, stream>>>(
        Y, bq, bk, bv, gama, fcb, ws, outp);
}